// Round 2
// baseline (946.442 us; speedup 1.0000x reference)
//
#include <hip/hip_runtime.h>

#define N0_SRC 495616
#define N0_DST 45056
#define E0 450560
#define N1_DST 4096
#define E1 40960
#define IN_FEATS 256
#define NH 128
#define NC 16

// ===================== CSR build for layer 0 =====================
// 4 edges per thread, int4 loads feeding the atomics.
__global__ void hist_kernel(const int4* __restrict__ dst4, int* __restrict__ cnt) {
    int t = blockIdx.x * blockDim.x + threadIdx.x;
    if (t < E0 / 4) {
        int4 d = dst4[t];
        atomicAdd(&cnt[d.x], 1);
        atomicAdd(&cnt[d.y], 1);
        atomicAdd(&cnt[d.z], 1);
        atomicAdd(&cnt[d.w], 1);
    }
}

// Single block, 1024 threads. cnt (45056) -> exclusive prefix into row_start and
// cursor (cnt overwritten in place as the scatter cursor). int4 phases: each
// thread's 44-int chunk starts at t*176 B (16B aligned), 11 int4 per chunk.
__global__ void __launch_bounds__(1024) scan_kernel(int* __restrict__ cnt,
                                                    int* __restrict__ row_start) {
    __shared__ int partial[1024];
    const int CH = N0_DST / 1024;  // 44
    int t = threadIdx.x;
    int base = t * CH;
    const int4* c4 = (const int4*)(cnt + base);
    int s = 0;
#pragma unroll
    for (int j = 0; j < CH / 4; j++) {
        int4 c = c4[j];
        s += c.x + c.y + c.z + c.w;
    }
    partial[t] = s;
    __syncthreads();
    for (int off = 1; off < 1024; off <<= 1) {
        int v = (t >= off) ? partial[t - off] : 0;
        __syncthreads();
        partial[t] += v;
        __syncthreads();
    }
    int run = partial[t] - s;  // exclusive prefix of this thread's chunk
    int4* r4 = (int4*)(row_start + base);
    int4* u4 = (int4*)(cnt + base);
#pragma unroll
    for (int j = 0; j < CH / 4; j++) {
        int4 c = c4[j];
        int4 r;
        r.x = run; run += c.x;
        r.y = run; run += c.y;
        r.z = run; run += c.z;
        r.w = run; run += c.w;
        r4[j] = r;   // row_start
        u4[j] = r;   // cursor starts at row offset
    }
    if (t == 1023) row_start[N0_DST] = run;  // == E0
}

// Scatter edges into CSR order, pre-gathering (src, w) so the aggregate kernel
// has a single 8B sequential load per edge. 4 edges/thread, vector input loads.
__global__ void scatter_kernel(const int4* __restrict__ dst4, const int4* __restrict__ src4,
                               const float4* __restrict__ w4, int* __restrict__ cursor,
                               int2* __restrict__ sw) {
    int t = blockIdx.x * blockDim.x + threadIdx.x;
    if (t < E0 / 4) {
        int4 d = dst4[t];
        int4 sc = src4[t];
        float4 w = w4[t];
        int p0 = atomicAdd(&cursor[d.x], 1);
        sw[p0] = make_int2(sc.x, __float_as_int(w.x));
        int p1 = atomicAdd(&cursor[d.y], 1);
        sw[p1] = make_int2(sc.y, __float_as_int(w.y));
        int p2 = atomicAdd(&cursor[d.z], 1);
        sw[p2] = make_int2(sc.z, __float_as_int(w.z));
        int p3 = atomicAdd(&cursor[d.w], 1);
        sw[p3] = make_int2(sc.w, __float_as_int(w.w));
    }
}

// ===================== Layer 0 aggregate (gather-only) =====================
// One wave (64 lanes) per dst node; float4 per lane = 256 feats in registers.
// Main loop: 4 edges/iter, no clamps (4 independent 1KB row loads in flight);
// scalar tail for the last 0-3 edges.
__global__ void __launch_bounds__(256) agg0_kernel(const float* __restrict__ x,
    const int2* __restrict__ sw, const int* __restrict__ row_start,
    float* __restrict__ hneigh) {
    int wv = blockIdx.x * 4 + (threadIdx.x >> 6);
    int lane = threadIdx.x & 63;
    if (wv >= N0_DST) return;
    int beg = row_start[wv], end = row_start[wv + 1];
    const float4* x4 = (const float4*)x;
    float4 xd = x4[(size_t)wv * 64 + lane];  // issue early, overlaps the loop
    float ax = 0.f, ay = 0.f, az = 0.f, aw = 0.f, degs = 0.f;
    int i = beg;
    for (; i + 4 <= end; i += 4) {
        int2 p0 = sw[i];
        int2 p1 = sw[i + 1];
        int2 p2 = sw[i + 2];
        int2 p3 = sw[i + 3];
        float4 v0 = x4[(size_t)p0.x * 64 + lane];
        float4 v1 = x4[(size_t)p1.x * 64 + lane];
        float4 v2 = x4[(size_t)p2.x * 64 + lane];
        float4 v3 = x4[(size_t)p3.x * 64 + lane];
        float w0 = __int_as_float(p0.y);
        float w1 = __int_as_float(p1.y);
        float w2 = __int_as_float(p2.y);
        float w3 = __int_as_float(p3.y);
        ax = fmaf(w0, v0.x, ax); ay = fmaf(w0, v0.y, ay);
        az = fmaf(w0, v0.z, az); aw = fmaf(w0, v0.w, aw);
        ax = fmaf(w1, v1.x, ax); ay = fmaf(w1, v1.y, ay);
        az = fmaf(w1, v1.z, az); aw = fmaf(w1, v1.w, aw);
        ax = fmaf(w2, v2.x, ax); ay = fmaf(w2, v2.y, ay);
        az = fmaf(w2, v2.z, az); aw = fmaf(w2, v2.w, aw);
        ax = fmaf(w3, v3.x, ax); ay = fmaf(w3, v3.y, ay);
        az = fmaf(w3, v3.z, az); aw = fmaf(w3, v3.w, aw);
        degs += w0 + w1 + w2 + w3;
    }
    for (; i < end; i++) {
        int2 p = sw[i];
        float4 v = x4[(size_t)p.x * 64 + lane];
        float w = __int_as_float(p.y);
        ax = fmaf(w, v.x, ax); ay = fmaf(w, v.y, ay);
        az = fmaf(w, v.z, az); aw = fmaf(w, v.w, aw);
        degs += w;
    }
    float inv = 1.0f / (degs + 1.0f);
    float4 r;
    r.x = (ax + xd.x) * inv; r.y = (ay + xd.y) * inv;
    r.z = (az + xd.z) * inv; r.w = (aw + xd.w) * inv;
    ((float4*)hneigh)[(size_t)wv * 64 + lane] = r;
}

// ===================== Layer 0 dense: h0 = relu(hneigh @ Wn0^T + bn0) ========
// 32 rows per block: halves per-block Wn0 refetch vs 16, 2x FMA per W element.
__global__ void __launch_bounds__(128) gemm0_kernel(const float* __restrict__ hneigh,
    const float* __restrict__ Wn, const float* __restrict__ bn,
    float* __restrict__ h0) {
    __shared__ float hn[32][IN_FEATS];  // 32 KB
    int nb = blockIdx.x * 32;
    int tid = threadIdx.x;
    const float4* s4 = (const float4*)(hneigh + (size_t)nb * IN_FEATS);
    float4* l4 = (float4*)&hn[0][0];
    for (int i = tid; i < 32 * IN_FEATS / 4; i += 128) l4[i] = s4[i];
    __syncthreads();
    float acc[32];
#pragma unroll
    for (int n = 0; n < 32; n++) acc[n] = 0.f;
    const float4* wr4 = (const float4*)(Wn + (size_t)tid * IN_FEATS);
#pragma unroll 2
    for (int k4 = 0; k4 < IN_FEATS / 4; k4++) {
        float4 wv = wr4[k4];
        int k = k4 * 4;
#pragma unroll
        for (int n = 0; n < 32; n++) {
            acc[n] += hn[n][k + 0] * wv.x;
            acc[n] += hn[n][k + 1] * wv.y;
            acc[n] += hn[n][k + 2] * wv.z;
            acc[n] += hn[n][k + 3] * wv.w;
        }
    }
    float b = bn[tid];
#pragma unroll
    for (int n = 0; n < 32; n++) {
        float v = acc[n] + b;
        h0[(size_t)(nb + n) * NH + tid] = v > 0.f ? v : 0.f;
    }
}

// ===================== Layer 1 edge scatter (agg1 is 2 MB -> L2-resident) ====
__global__ void edge1_kernel(const float* __restrict__ h0,
                             const int* __restrict__ src, const int* __restrict__ dst,
                             const float* __restrict__ w,
                             float* __restrict__ agg, float* __restrict__ deg) {
    int t = blockIdx.x * blockDim.x + threadIdx.x;
    int e = t >> 5;
    int lane = t & 31;
    if (e >= E1) return;
    int s = src[e], d = dst[e];
    float we = w[e];
    float4 v = ((const float4*)(h0 + (size_t)s * NH))[lane];
    float* ad = agg + (size_t)d * NH + lane * 4;
    unsafeAtomicAdd(ad + 0, v.x * we);
    unsafeAtomicAdd(ad + 1, v.y * we);
    unsafeAtomicAdd(ad + 2, v.z * we);
    unsafeAtomicAdd(ad + 3, v.w * we);
    if (lane == 0) unsafeAtomicAdd(deg + d, we);
}

// ===================== Layer 1 dense ========================================
__global__ void __launch_bounds__(128) gemm1_kernel(const float* __restrict__ h0,
    const float* __restrict__ agg, const float* __restrict__ deg,
    const float* __restrict__ Wn, const float* __restrict__ bn,
    float* __restrict__ h1) {
    __shared__ float hn[8][NH];
    int nb = blockIdx.x * 8;
    int tid = threadIdx.x;
    for (int i = tid; i < 8 * NH; i += 128) {
        int n = i >> 7;
        int k = i & 127;
        int m = nb + n;
        float hv = agg[(size_t)m * NH + k] + h0[(size_t)m * NH + k];
        hn[n][k] = hv / (deg[m] + 1.0f);
    }
    __syncthreads();
    float acc[8];
#pragma unroll
    for (int n = 0; n < 8; n++) acc[n] = 0.f;
    const float4* wr4 = (const float4*)(Wn + (size_t)tid * NH);
#pragma unroll 4
    for (int k4 = 0; k4 < NH / 4; k4++) {
        float4 wv = wr4[k4];
        int k = k4 * 4;
#pragma unroll
        for (int n = 0; n < 8; n++) {
            acc[n] += hn[n][k + 0] * wv.x;
            acc[n] += hn[n][k + 1] * wv.y;
            acc[n] += hn[n][k + 2] * wv.z;
            acc[n] += hn[n][k + 3] * wv.w;
        }
    }
    float b = bn[tid];
#pragma unroll
    for (int n = 0; n < 8; n++) {
        float v = acc[n] + b;
        h1[(size_t)(nb + n) * NH + tid] = v > 0.f ? v : 0.f;
    }
}

// ===================== Final FC =============================================
__global__ void fc_kernel(const float* __restrict__ h1, const float* __restrict__ Wfc,
                          const float* __restrict__ bfc, float* __restrict__ out) {
    int t = blockIdx.x * blockDim.x + threadIdx.x;
    int m = t >> 4, c = t & 15;
    if (m >= N1_DST) return;
    const float4* hr = (const float4*)(h1 + (size_t)m * NH);
    const float4* wr = (const float4*)(Wfc + (size_t)c * NH);
    float acc = 0.f;
#pragma unroll 8
    for (int k = 0; k < NH / 4; k++) {
        float4 a = hr[k];
        float4 b = wr[k];
        acc += a.x * b.x + a.y * b.y + a.z * b.z + a.w * b.w;
    }
    out[t] = acc + bfc[c];
}

extern "C" void kernel_launch(void* const* d_in, const int* in_sizes, int n_in,
                              void* d_out, int out_size, void* d_ws, size_t ws_size,
                              hipStream_t stream) {
    const float* x   = (const float*)d_in[0];
    const int* src0  = (const int*)d_in[1];
    const int* dst0  = (const int*)d_in[2];
    const float* w0  = (const float*)d_in[3];
    const int* src1  = (const int*)d_in[4];
    const int* dst1  = (const int*)d_in[5];
    const float* w1  = (const float*)d_in[6];
    const float* Wn0 = (const float*)d_in[7];
    const float* bn0 = (const float*)d_in[8];
    const float* Wn1 = (const float*)d_in[9];
    const float* bn1 = (const float*)d_in[10];
    const float* Wfc = (const float*)d_in[11];
    const float* bfc = (const float*)d_in[12];
    float* out = (float*)d_out;

    // workspace layout (4-byte units). Liveness-based aliasing:
    //   sw (902K ints, dead after agg0)  aliases h0 (written by gemm0, after agg0)
    //   h1 (524K, written by gemm1)      aliases hneigh (dead after gemm0)
    float* ws = (float*)d_ws;
    float* agg1      = ws;                            // 524288
    float* deg1      = agg1 + (size_t)N1_DST * NH;    // 4096
    int*   cnt       = (int*)(deg1 + N1_DST);         // 45056 (becomes cursor)
    int*   row_start = cnt + N0_DST;                  // 45057 (+pad)
    float* hneigh    = ws + 618500;                   // 11534336, 16B-aligned
    float* h0        = ws + 12152836;                 // 5767168, 16B-aligned
    int2*  sw        = (int2*)h0;                     // 901120 ints (alias)
    float* h1        = hneigh;                        // 524288 (alias)

    // zero agg1 + deg1 + cnt in one shot (contiguous)
    size_t zero_floats = (size_t)N1_DST * NH + N1_DST + N0_DST;
    hipMemsetAsync(d_ws, 0, zero_floats * sizeof(float), stream);

    // CSR build for layer 0 (scatter pre-gathers (src,w) into CSR order)
    hist_kernel<<<(E0 / 4 + 255) / 256, 256, 0, stream>>>((const int4*)dst0, cnt);
    scan_kernel<<<1, 1024, 0, stream>>>(cnt, row_start);
    scatter_kernel<<<(E0 / 4 + 255) / 256, 256, 0, stream>>>(
        (const int4*)dst0, (const int4*)src0, (const float4*)w0, cnt, sw);

    // layer 0: gather-aggregate (MLP x4), then dense (32 rows/block)
    agg0_kernel<<<(N0_DST + 3) / 4, 256, 0, stream>>>(x, sw, row_start, hneigh);
    gemm0_kernel<<<N0_DST / 32, 128, 0, stream>>>(hneigh, Wn0, bn0, h0);

    // layer 1
    edge1_kernel<<<(E1 * 32) / 256, 256, 0, stream>>>(h0, src1, dst1, w1, agg1, deg1);
    gemm1_kernel<<<N1_DST / 8, 128, 0, stream>>>(h0, agg1, deg1, Wn1, bn1, h1);

    // fc
    fc_kernel<<<(N1_DST * NC) / 256, 256, 0, stream>>>(h1, Wfc, bfc, out);
}

// Round 3
// 904.323 us; speedup vs baseline: 1.0466x; 1.0466x over previous
//
#include <hip/hip_runtime.h>

#define N0_SRC 495616
#define N0_DST 45056
#define E0 450560
#define N1_DST 4096
#define E1 40960
#define IN_FEATS 256
#define NH 128
#define NC 16

// ===================== CSR build for layer 0 =====================
// 4 edges per thread, int4 loads feeding the atomics.
__global__ void hist_kernel(const int4* __restrict__ dst4, int* __restrict__ cnt) {
    int t = blockIdx.x * blockDim.x + threadIdx.x;
    if (t < E0 / 4) {
        int4 d = dst4[t];
        atomicAdd(&cnt[d.x], 1);
        atomicAdd(&cnt[d.y], 1);
        atomicAdd(&cnt[d.z], 1);
        atomicAdd(&cnt[d.w], 1);
    }
}

// Single block, 1024 threads. cnt (45056) -> exclusive prefix into row_start and
// cursor (cnt overwritten in place as the scatter cursor). int4 phases: each
// thread's 44-int chunk starts at t*176 B (16B aligned), 11 int4 per chunk.
__global__ void __launch_bounds__(1024) scan_kernel(int* __restrict__ cnt,
                                                    int* __restrict__ row_start) {
    __shared__ int partial[1024];
    const int CH = N0_DST / 1024;  // 44
    int t = threadIdx.x;
    int base = t * CH;
    const int4* c4 = (const int4*)(cnt + base);
    int s = 0;
#pragma unroll
    for (int j = 0; j < CH / 4; j++) {
        int4 c = c4[j];
        s += c.x + c.y + c.z + c.w;
    }
    partial[t] = s;
    __syncthreads();
    for (int off = 1; off < 1024; off <<= 1) {
        int v = (t >= off) ? partial[t - off] : 0;
        __syncthreads();
        partial[t] += v;
        __syncthreads();
    }
    int run = partial[t] - s;  // exclusive prefix of this thread's chunk
    int4* r4 = (int4*)(row_start + base);
    int4* u4 = (int4*)(cnt + base);
#pragma unroll
    for (int j = 0; j < CH / 4; j++) {
        int4 c = c4[j];
        int4 r;
        r.x = run; run += c.x;
        r.y = run; run += c.y;
        r.z = run; run += c.z;
        r.w = run; run += c.w;
        r4[j] = r;   // row_start
        u4[j] = r;   // cursor starts at row offset
    }
    if (t == 1023) row_start[N0_DST] = run;  // == E0
}

// Scatter edges into CSR order, pre-gathering (src, w) so the aggregate kernel
// has a single 8B sequential load per edge. 4 edges/thread, vector input loads.
__global__ void scatter_kernel(const int4* __restrict__ dst4, const int4* __restrict__ src4,
                               const float4* __restrict__ w4, int* __restrict__ cursor,
                               int2* __restrict__ sw) {
    int t = blockIdx.x * blockDim.x + threadIdx.x;
    if (t < E0 / 4) {
        int4 d = dst4[t];
        int4 sc = src4[t];
        float4 w = w4[t];
        int p0 = atomicAdd(&cursor[d.x], 1);
        sw[p0] = make_int2(sc.x, __float_as_int(w.x));
        int p1 = atomicAdd(&cursor[d.y], 1);
        sw[p1] = make_int2(sc.y, __float_as_int(w.y));
        int p2 = atomicAdd(&cursor[d.z], 1);
        sw[p2] = make_int2(sc.z, __float_as_int(w.z));
        int p3 = atomicAdd(&cursor[d.w], 1);
        sw[p3] = make_int2(sc.w, __float_as_int(w.w));
    }
}

// ===================== Layer 0 aggregate (gather-only) =====================
// One wave (64 lanes) per dst node; float4 per lane = 256 feats in registers.
// Main loop: 4 edges/iter, no clamps (4 independent 1KB row loads in flight);
// scalar tail for the last 0-3 edges.
__global__ void __launch_bounds__(256) agg0_kernel(const float* __restrict__ x,
    const int2* __restrict__ sw, const int* __restrict__ row_start,
    float* __restrict__ hneigh) {
    int wv = blockIdx.x * 4 + (threadIdx.x >> 6);
    int lane = threadIdx.x & 63;
    if (wv >= N0_DST) return;
    int beg = row_start[wv], end = row_start[wv + 1];
    const float4* x4 = (const float4*)x;
    float4 xd = x4[(size_t)wv * 64 + lane];  // issue early, overlaps the loop
    float ax = 0.f, ay = 0.f, az = 0.f, aw = 0.f, degs = 0.f;
    int i = beg;
    for (; i + 4 <= end; i += 4) {
        int2 p0 = sw[i];
        int2 p1 = sw[i + 1];
        int2 p2 = sw[i + 2];
        int2 p3 = sw[i + 3];
        float4 v0 = x4[(size_t)p0.x * 64 + lane];
        float4 v1 = x4[(size_t)p1.x * 64 + lane];
        float4 v2 = x4[(size_t)p2.x * 64 + lane];
        float4 v3 = x4[(size_t)p3.x * 64 + lane];
        float w0 = __int_as_float(p0.y);
        float w1 = __int_as_float(p1.y);
        float w2 = __int_as_float(p2.y);
        float w3 = __int_as_float(p3.y);
        ax = fmaf(w0, v0.x, ax); ay = fmaf(w0, v0.y, ay);
        az = fmaf(w0, v0.z, az); aw = fmaf(w0, v0.w, aw);
        ax = fmaf(w1, v1.x, ax); ay = fmaf(w1, v1.y, ay);
        az = fmaf(w1, v1.z, az); aw = fmaf(w1, v1.w, aw);
        ax = fmaf(w2, v2.x, ax); ay = fmaf(w2, v2.y, ay);
        az = fmaf(w2, v2.z, az); aw = fmaf(w2, v2.w, aw);
        ax = fmaf(w3, v3.x, ax); ay = fmaf(w3, v3.y, ay);
        az = fmaf(w3, v3.z, az); aw = fmaf(w3, v3.w, aw);
        degs += w0 + w1 + w2 + w3;
    }
    for (; i < end; i++) {
        int2 p = sw[i];
        float4 v = x4[(size_t)p.x * 64 + lane];
        float w = __int_as_float(p.y);
        ax = fmaf(w, v.x, ax); ay = fmaf(w, v.y, ay);
        az = fmaf(w, v.z, az); aw = fmaf(w, v.w, aw);
        degs += w;
    }
    float inv = 1.0f / (degs + 1.0f);
    float4 r;
    r.x = (ax + xd.x) * inv; r.y = (ay + xd.y) * inv;
    r.z = (az + xd.z) * inv; r.w = (aw + xd.w) * inv;
    ((float4*)hneigh)[(size_t)wv * 64 + lane] = r;
}

// ===================== Layer 0 dense: h0 = relu(hneigh @ Wn0^T + bn0) ========
// 16 rows per block (the R1 config: 16 KB LDS -> 10 blocks/CU, grid 2816).
__global__ void __launch_bounds__(128) gemm0_kernel(const float* __restrict__ hneigh,
    const float* __restrict__ Wn, const float* __restrict__ bn,
    float* __restrict__ h0) {
    __shared__ float hn[16][IN_FEATS];
    int nb = blockIdx.x * 16;
    int tid = threadIdx.x;
    const float4* s4 = (const float4*)(hneigh + (size_t)nb * IN_FEATS);
    float4* l4 = (float4*)&hn[0][0];
    for (int i = tid; i < 16 * IN_FEATS / 4; i += 128) l4[i] = s4[i];
    __syncthreads();
    float acc[16];
#pragma unroll
    for (int n = 0; n < 16; n++) acc[n] = 0.f;
    const float4* wr4 = (const float4*)(Wn + (size_t)tid * IN_FEATS);
#pragma unroll 4
    for (int k4 = 0; k4 < IN_FEATS / 4; k4++) {
        float4 wv = wr4[k4];
        int k = k4 * 4;
#pragma unroll
        for (int n = 0; n < 16; n++) {
            acc[n] += hn[n][k + 0] * wv.x;
            acc[n] += hn[n][k + 1] * wv.y;
            acc[n] += hn[n][k + 2] * wv.z;
            acc[n] += hn[n][k + 3] * wv.w;
        }
    }
    float b = bn[tid];
#pragma unroll
    for (int n = 0; n < 16; n++) {
        float v = acc[n] + b;
        h0[(size_t)(nb + n) * NH + tid] = v > 0.f ? v : 0.f;
    }
}

// ===================== Layer 1 edge scatter (agg1 is 2 MB -> L2-resident) ====
__global__ void edge1_kernel(const float* __restrict__ h0,
                             const int* __restrict__ src, const int* __restrict__ dst,
                             const float* __restrict__ w,
                             float* __restrict__ agg, float* __restrict__ deg) {
    int t = blockIdx.x * blockDim.x + threadIdx.x;
    int e = t >> 5;
    int lane = t & 31;
    if (e >= E1) return;
    int s = src[e], d = dst[e];
    float we = w[e];
    float4 v = ((const float4*)(h0 + (size_t)s * NH))[lane];
    float* ad = agg + (size_t)d * NH + lane * 4;
    unsafeAtomicAdd(ad + 0, v.x * we);
    unsafeAtomicAdd(ad + 1, v.y * we);
    unsafeAtomicAdd(ad + 2, v.z * we);
    unsafeAtomicAdd(ad + 3, v.w * we);
    if (lane == 0) unsafeAtomicAdd(deg + d, we);
}

// ===================== Layer 1 dense (16 rows/block) =========================
__global__ void __launch_bounds__(128) gemm1_kernel(const float* __restrict__ h0,
    const float* __restrict__ agg, const float* __restrict__ deg,
    const float* __restrict__ Wn, const float* __restrict__ bn,
    float* __restrict__ h1) {
    __shared__ float hn[16][NH];  // 8 KB
    int nb = blockIdx.x * 16;
    int tid = threadIdx.x;
    for (int i = tid; i < 16 * NH; i += 128) {
        int n = i >> 7;
        int k = i & 127;
        int m = nb + n;
        float hv = agg[(size_t)m * NH + k] + h0[(size_t)m * NH + k];
        hn[n][k] = hv / (deg[m] + 1.0f);
    }
    __syncthreads();
    float acc[16];
#pragma unroll
    for (int n = 0; n < 16; n++) acc[n] = 0.f;
    const float4* wr4 = (const float4*)(Wn + (size_t)tid * NH);
#pragma unroll 4
    for (int k4 = 0; k4 < NH / 4; k4++) {
        float4 wv = wr4[k4];
        int k = k4 * 4;
#pragma unroll
        for (int n = 0; n < 16; n++) {
            acc[n] += hn[n][k + 0] * wv.x;
            acc[n] += hn[n][k + 1] * wv.y;
            acc[n] += hn[n][k + 2] * wv.z;
            acc[n] += hn[n][k + 3] * wv.w;
        }
    }
    float b = bn[tid];
#pragma unroll
    for (int n = 0; n < 16; n++) {
        float v = acc[n] + b;
        h1[(size_t)(nb + n) * NH + tid] = v > 0.f ? v : 0.f;
    }
}

// ===================== Final FC =============================================
__global__ void fc_kernel(const float* __restrict__ h1, const float* __restrict__ Wfc,
                          const float* __restrict__ bfc, float* __restrict__ out) {
    int t = blockIdx.x * blockDim.x + threadIdx.x;
    int m = t >> 4, c = t & 15;
    if (m >= N1_DST) return;
    const float4* hr = (const float4*)(h1 + (size_t)m * NH);
    const float4* wr = (const float4*)(Wfc + (size_t)c * NH);
    float acc = 0.f;
#pragma unroll 8
    for (int k = 0; k < NH / 4; k++) {
        float4 a = hr[k];
        float4 b = wr[k];
        acc += a.x * b.x + a.y * b.y + a.z * b.z + a.w * b.w;
    }
    out[t] = acc + bfc[c];
}

extern "C" void kernel_launch(void* const* d_in, const int* in_sizes, int n_in,
                              void* d_out, int out_size, void* d_ws, size_t ws_size,
                              hipStream_t stream) {
    const float* x   = (const float*)d_in[0];
    const int* src0  = (const int*)d_in[1];
    const int* dst0  = (const int*)d_in[2];
    const float* w0  = (const float*)d_in[3];
    const int* src1  = (const int*)d_in[4];
    const int* dst1  = (const int*)d_in[5];
    const float* w1  = (const float*)d_in[6];
    const float* Wn0 = (const float*)d_in[7];
    const float* bn0 = (const float*)d_in[8];
    const float* Wn1 = (const float*)d_in[9];
    const float* bn1 = (const float*)d_in[10];
    const float* Wfc = (const float*)d_in[11];
    const float* bfc = (const float*)d_in[12];
    float* out = (float*)d_out;

    // workspace layout (4-byte units). Liveness-based aliasing:
    //   sw (902K ints, dead after agg0)  aliases h0 (written by gemm0, after agg0)
    //   h1 (524K, written by gemm1)      aliases hneigh (dead after gemm0)
    float* ws = (float*)d_ws;
    float* agg1      = ws;                            // 524288
    float* deg1      = agg1 + (size_t)N1_DST * NH;    // 4096
    int*   cnt       = (int*)(deg1 + N1_DST);         // 45056 (becomes cursor)
    int*   row_start = cnt + N0_DST;                  // 45057 (+pad)
    float* hneigh    = ws + 618500;                   // 11534336, 16B-aligned
    float* h0        = ws + 12152836;                 // 5767168, 16B-aligned
    int2*  sw        = (int2*)h0;                     // 901120 ints (alias)
    float* h1        = hneigh;                        // 524288 (alias)

    // zero agg1 + deg1 + cnt in one shot (contiguous)
    size_t zero_floats = (size_t)N1_DST * NH + N1_DST + N0_DST;
    hipMemsetAsync(d_ws, 0, zero_floats * sizeof(float), stream);

    // CSR build for layer 0 (scatter pre-gathers (src,w) into CSR order)
    hist_kernel<<<(E0 / 4 + 255) / 256, 256, 0, stream>>>((const int4*)dst0, cnt);
    scan_kernel<<<1, 1024, 0, stream>>>(cnt, row_start);
    scatter_kernel<<<(E0 / 4 + 255) / 256, 256, 0, stream>>>(
        (const int4*)dst0, (const int4*)src0, (const float4*)w0, cnt, sw);

    // layer 0: gather-aggregate (MLP x4), then dense (16 rows/block)
    agg0_kernel<<<(N0_DST + 3) / 4, 256, 0, stream>>>(x, sw, row_start, hneigh);
    gemm0_kernel<<<N0_DST / 16, 128, 0, stream>>>(hneigh, Wn0, bn0, h0);

    // layer 1
    edge1_kernel<<<(E1 * 32) / 256, 256, 0, stream>>>(h0, src1, dst1, w1, agg1, deg1);
    gemm1_kernel<<<N1_DST / 16, 128, 0, stream>>>(h0, agg1, deg1, Wn1, bn1, h1);

    // fc
    fc_kernel<<<(N1_DST * NC) / 256, 256, 0, stream>>>(h1, Wfc, bfc, out);
}